// Round 10
// baseline (673.196 us; speedup 1.0000x reference)
//
#include <hip/hip_runtime.h>
#include <math.h>

// Matrix-Tree marginals: probs[b,i,j] = A[i,j]*(X[i-1,i-1] - (j>=1 ? X[j-1,i-1] : 0))
// X = inv(M) via blocked in-place Gauss-Jordan (4 panel steps of 64, SDD -> no pivoting).
// Round-10: round-9 column-split step + PING-PONG Fbuf. Round-9's single Fbuf raced:
// next-owner block's dual-writes (phase-2 pivot rows, phase-3 epilogue) overwrote rows the
// partner block was still reading for its own phase 1 / phase-3 staging. Now step kb reads
// F[kb&1] and writes F[(kb+1)&1]; nothing is read+written in one launch.
// F[2] aliases d_out exactly (2 x 256 x 256 x 64 doubles = 67,108,864 B = |d_out|), both
// fully rewritten by k_xt/k_epi2 afterwards.
// ws (doubles): M[B][256][256] | mb[B] | nb[B](int) | Dg[B][256]; partial aliases Dg.

#define S 256
#define BB 256

__device__ __forceinline__ int rowmap(int lr, int kb) {   // local 0..191 -> global row skipping panel kb
    int rt = lr >> 6;
    int rb = rt + (rt >= kb ? 1 : 0);
    return rb * 64 + (lr & 63);
}

// ---------------- kernel 1a: dense max over each batch's full 256x256 score matrix ----------
__global__ __launch_bounds__(256) void k_max(const float* __restrict__ sc,
                                             float* __restrict__ partial) {
    int b = blockIdx.y, rg = blockIdx.x;                 // 8 row-groups of 32 rows
    const float4* p4 = (const float4*)(sc + (size_t)b * S * S + rg * 8192);
    int tid = threadIdx.x;
    float4 v[8];
    #pragma unroll
    for (int it = 0; it < 8; ++it) v[it] = p4[tid + 256 * it];
    float m = -1e30f;
    #pragma unroll
    for (int it = 0; it < 8; ++it)
        m = fmaxf(m, fmaxf(fmaxf(v[it].x, v[it].y), fmaxf(v[it].z, v[it].w)));
    for (int off = 32; off > 0; off >>= 1) m = fmaxf(m, __shfl_down(m, off));
    __shared__ float sm[4];
    if ((tid & 63) == 0) sm[tid >> 6] = m;
    __syncthreads();
    if (tid == 0) partial[b * 8 + rg] = fmaxf(fmaxf(sm[0], sm[1]), fmaxf(sm[2], sm[3]));
}

// ---------------- kernel 1b: per-batch n (mask count) + combine partial maxima --------------
__global__ void k_n(const unsigned char* __restrict__ mk, const float* __restrict__ partial,
                    double* __restrict__ mb, int* __restrict__ nb) {
    int b = blockIdx.x, j = threadIdx.x;
    __shared__ int shc[4];

    const unsigned int* mw = (const unsigned int*)mk;    // sniff mask dtype
    unsigned int w0 = mw[0], w1 = mw[1];
    int mode = (w0 != 0u) ? 0 : ((w1 != 0u) ? 1 : 2);

    int c;
    if (mode == 0)      c = (mk[(size_t)b * S + j] != 0);
    else if (mode == 1) c = (((const int*)mk)[(size_t)b * S + j] != 0);
    else                c = (((const long long*)mk)[(size_t)b * S + j] != 0LL);

    int lane = j & 63, wid = j >> 6;
    int cs = c;
    for (int off = 32; off > 0; off >>= 1) cs += __shfl_down(cs, off);
    if (lane == 0) shc[wid] = cs;
    __syncthreads();
    if (j == 0) {
        nb[b] = shc[0] + shc[1] + shc[2] + shc[3];
        float mm = partial[b * 8];
        #pragma unroll
        for (int q = 1; q < 8; ++q) mm = fmaxf(mm, partial[b * 8 + q]);
        mb[b] = (double)mm;
    }
}

// ---------------- kernel 2: build padded M (f64, expf), 4 rows/block; dual-write F0 ---------
__global__ __launch_bounds__(256) void k_build(const float* __restrict__ sc,
                                               const double* __restrict__ mb,
                                               const int* __restrict__ nb,
                                               double* __restrict__ Mg,
                                               double* __restrict__ Fb) {
    int b = blockIdx.y;
    int wid = threadIdx.x >> 6, lane = threadIdx.x & 63;
    int p = blockIdx.x * 4 + wid;
    int n = nb[b];
    double m = mb[b];
    __shared__ double se[4][260];
    double* Mrow = Mg + ((size_t)b * S + p) * S;
    bool act = (p < n);
    double ssum = 0.0;
    #pragma unroll
    for (int c4 = 0; c4 < 4; ++c4) {
        int j = lane + 64 * c4;
        double ev = 0.0;
        if (act && j <= n)
            ev = (double)expf((float)((double)sc[((size_t)b * S + (p + 1)) * S + j] - m));
        se[wid][j] = ev;
        ssum += ev;
    }
    for (int off = 32; off > 0; off >>= 1) ssum += __shfl_down(ssum, off);
    ssum = __shfl(ssum, 0);
    __syncthreads();                       // uniform: all 4 waves reach it
    #pragma unroll
    for (int c4 = 0; c4 < 4; ++c4) {
        int j = lane + 64 * c4;
        double v;
        if (act && j < n) v = ((j == p) ? ssum : 0.0) - se[wid][j + 1];
        else              v = (j == p) ? 1.0 : 0.0;
        Mrow[j] = v;
        if (c4 == 0)                       // j < 64: step-0 pivot panel copy
            Fb[((size_t)b * S + p) * 64 + j] = v;
    }
}

// ---------------- kernel 3: fused column-split panel step (ping-pong F) ---------------------
__global__ __launch_bounds__(512, 4) void k_step2(double* __restrict__ Mg,
                                                  const double* __restrict__ Fcur,
                                                  double* __restrict__ Fnext, int kb) {
    int id = blockIdx.x;
    int q = id & 1, b = id >> 1;           // q: column half [128q, 128q+128)
    double* M = Mg + (size_t)b * S * S;
    const double* F = Fcur + (size_t)b * (S * 64);   // F[r][k] = old M[r][64kb+k]
    double* FN = Fnext + (size_t)b * (S * 64);       // next step's panel (written only)
    int tid = threadIdx.x;
    __shared__ double H[64 * 128];         // H[r][jl], own cols
    __shared__ double SCR[1584];           // union: GJ bufs(256) | PT(528)+Rc(1056) | FT(1552)

    // ---- phase 1: register GJ on the 64x64 diag block (from Fcur) ----
    int i = tid >> 3, g = tid & 7, c0 = g << 3;
    double c[8];
    {
        const double* src = F + (size_t)(kb * 64 + i) * 64 + c0;
        #pragma unroll
        for (int m2 = 0; m2 < 4; ++m2) {
            double2 t = *(const double2*)(src + 2 * m2);
            c[2 * m2] = t.x; c[2 * m2 + 1] = t.y;
        }
    }
    double* rbuf = SCR;          // [2][64]
    double* cbuf = SCR + 128;    // [2][64]
    if (i == 0) {
        #pragma unroll
        for (int u = 0; u < 8; ++u) rbuf[c0 + u] = c[u];
    }
    if (g == 0) cbuf[i] = c[0];
    for (int k = 0; k < 64; ++k) {
        int par = k & 1;
        __syncthreads();
        double pv = rbuf[par * 64 + k];
        double f  = cbuf[par * 64 + i];
        double rk[8];
        #pragma unroll
        for (int m2 = 0; m2 < 4; ++m2) {
            double2 t = *(const double2*)&rbuf[par * 64 + c0 + 2 * m2];
            rk[2 * m2] = t.x; rk[2 * m2 + 1] = t.y;
        }
        double pivinv = 1.0 / pv;
        int kg = k >> 3, ks = k & 7;
        if (i == k) {
            #pragma unroll
            for (int u = 0; u < 8; ++u)
                c[u] = ((g == kg) && (u == ks)) ? pivinv : c[u] * pivinv;
        } else {
            double gm = f * pivinv;
            #pragma unroll
            for (int u = 0; u < 8; ++u)
                c[u] = ((g == kg) && (u == ks)) ? (-gm) : fma(-gm, rk[u], c[u]);
        }
        int k1 = k + 1;
        if (k1 < 64) {
            if (i == k1) {
                #pragma unroll
                for (int u = 0; u < 8; ++u) rbuf[(par ^ 1) * 64 + c0 + u] = c[u];
            }
            if (g == (k1 >> 3)) cbuf[(par ^ 1) * 64 + i] = c[k1 & 7];
        }
    }
    // threads hold Pinv[i][c0..c0+7] in c[]

    // ---- phase 2: H(own 128 cols) = Pinv * R_old (8-k chunks); owner plants Pinv ----
    int ty = tid >> 5, tx = tid & 31;      // ty 0..15 (4 rows each), tx 0..31 (col pairs)
    double* PT = SCR;                      // PT[kL*66 + t] = Pinv[t][cs*8+kL]
    double* Rc = SCR + 528;                // Rc[kL*132 + jl]
    double2 ga[4][2];
    #pragma unroll
    for (int r = 0; r < 4; ++r) { ga[r][0] = double2{0.0, 0.0}; ga[r][1] = double2{0.0, 0.0}; }

    for (int cs2 = 0; cs2 < 8; ++cs2) {
        __syncthreads();                   // prior SCR reads done (covers GJ tail on cs2=0)
        if (g == cs2) {
            #pragma unroll
            for (int u = 0; u < 8; ++u) PT[u * 66 + i] = c[u];
        }
        #pragma unroll
        for (int rep = 0; rep < 2; ++rep) {
            int idx = rep * 512 + tid;
            int kL = idx >> 7, jl = idx & 127;
            Rc[kL * 132 + jl] = M[(size_t)(kb * 64 + cs2 * 8 + kL) * S + 128 * q + jl];
        }
        __syncthreads();
        #pragma unroll
        for (int kL = 0; kL < 8; ++kL) {
            double2 pA = *(const double2*)&PT[kL * 66 + 4 * ty];
            double2 pB = *(const double2*)&PT[kL * 66 + 4 * ty + 2];
            double2 r0 = *(const double2*)&Rc[kL * 132 + 2 * tx];
            double2 r1 = *(const double2*)&Rc[kL * 132 + 2 * tx + 64];
            ga[0][0].x = fma(pA.x, r0.x, ga[0][0].x); ga[0][0].y = fma(pA.x, r0.y, ga[0][0].y);
            ga[0][1].x = fma(pA.x, r1.x, ga[0][1].x); ga[0][1].y = fma(pA.x, r1.y, ga[0][1].y);
            ga[1][0].x = fma(pA.y, r0.x, ga[1][0].x); ga[1][0].y = fma(pA.y, r0.y, ga[1][0].y);
            ga[1][1].x = fma(pA.y, r1.x, ga[1][1].x); ga[1][1].y = fma(pA.y, r1.y, ga[1][1].y);
            ga[2][0].x = fma(pB.x, r0.x, ga[2][0].x); ga[2][0].y = fma(pB.x, r0.y, ga[2][0].y);
            ga[2][1].x = fma(pB.x, r1.x, ga[2][1].x); ga[2][1].y = fma(pB.x, r1.y, ga[2][1].y);
            ga[3][0].x = fma(pB.y, r0.x, ga[3][0].x); ga[3][0].y = fma(pB.y, r0.y, ga[3][0].y);
            ga[3][1].x = fma(pB.y, r1.x, ga[3][1].x); ga[3][1].y = fma(pB.y, r1.y, ga[3][1].y);
        }
    }
    // H <- GEMM result (owner's pivot cols overwritten by Pinv below)
    #pragma unroll
    for (int r = 0; r < 4; ++r) {
        int row = 4 * ty + r;
        *(double2*)&H[row * 128 + 2 * tx]      = ga[r][0];
        *(double2*)&H[row * 128 + 64 + 2 * tx] = ga[r][1];
    }
    int qp = kb >> 1, po = (kb & 1) << 6;  // current pivot owner half, local offset
    __syncthreads();
    if (q == qp) {
        #pragma unroll
        for (int u = 0; u < 8; ++u) H[i * 128 + po + c0 + u] = c[u];
    }
    __syncthreads();                       // H final
    // writeback pivot rows (own cols) to M
    #pragma unroll
    for (int rep = 0; rep < 8; ++rep) {
        int idx = rep * 512 + tid;         // 0..4095 (64 rows x 64 double2)
        int row = idx >> 6, cp = idx & 63;
        *(double2*)&M[(size_t)(kb * 64 + row) * S + 128 * q + 2 * cp] =
            *(const double2*)&H[row * 128 + 2 * cp];
    }
    int kbn = kb + 1, qn = kbn >> 1, pon = (kbn & 1) << 6;
    if (kb < 3 && q == qn) {               // next-step Fnext: pivot-row part
        #pragma unroll
        for (int rep = 0; rep < 4; ++rep) {
            int idx = rep * 512 + tid;     // 0..2047 (64 rows x 32 double2)
            int row = idx >> 5, kp = idx & 31;
            *(double2*)&FN[(size_t)(kb * 64 + row) * 64 + 2 * kp] =
                *(const double2*)&H[row * 128 + pon + 2 * kp];
        }
    }

    // ---- phase 3: 192 non-pivot rows x own 128 cols: M = (pivotcol?0:M) - F*H ----
    int tz = tid >> 4, txx = tid & 15;     // tz 0..31 (6 rows each), txx 0..15 (8 cols)
    double* FT = SCR;                      // FT[kk*194 + lr] = F[rowmap(lr)][ck*8+kk]
    double2 acc[6][4];
    #pragma unroll
    for (int h = 0; h < 6; ++h)
        #pragma unroll
        for (int w = 0; w < 4; ++w) acc[h][w] = double2{0.0, 0.0};

    for (int ck = 0; ck < 8; ++ck) {
        __syncthreads();                   // prior SCR reads done
        #pragma unroll
        for (int rep = 0; rep < 3; ++rep) {
            int idx = rep * 512 + tid;     // 0..1535
            int lr = idx >> 3, kk = idx & 7;
            FT[kk * 194 + lr] = F[(size_t)rowmap(lr, kb) * 64 + ck * 8 + kk];
        }
        __syncthreads();
        #pragma unroll
        for (int kk = 0; kk < 8; ++kk) {
            int kr = ck * 8 + kk;
            double2 fA = *(const double2*)&FT[kk * 194 + 6 * tz];
            double2 fB = *(const double2*)&FT[kk * 194 + 6 * tz + 2];
            double2 fC = *(const double2*)&FT[kk * 194 + 6 * tz + 4];
            #pragma unroll
            for (int w = 0; w < 4; ++w) {
                double2 h2 = *(const double2*)&H[kr * 128 + 2 * txx + 32 * w];
                acc[0][w].x = fma(fA.x, h2.x, acc[0][w].x); acc[0][w].y = fma(fA.x, h2.y, acc[0][w].y);
                acc[1][w].x = fma(fA.y, h2.x, acc[1][w].x); acc[1][w].y = fma(fA.y, h2.y, acc[1][w].y);
                acc[2][w].x = fma(fB.x, h2.x, acc[2][w].x); acc[2][w].y = fma(fB.x, h2.y, acc[2][w].y);
                acc[3][w].x = fma(fB.y, h2.x, acc[3][w].x); acc[3][w].y = fma(fB.y, h2.y, acc[3][w].y);
                acc[4][w].x = fma(fC.x, h2.x, acc[4][w].x); acc[4][w].y = fma(fC.x, h2.y, acc[4][w].y);
                acc[5][w].x = fma(fC.y, h2.x, acc[5][w].x); acc[5][w].y = fma(fC.y, h2.y, acc[5][w].y);
            }
        }
    }
    // epilogue: own rows/cols RMW; pivot cols get -acc; dual-write next-step Fnext
    bool own_piv  = (q == qp);
    bool own_next = (kb < 3 && q == qn);
    #pragma unroll
    for (int h = 0; h < 6; ++h) {
        int lr = 6 * tz + h;
        size_t grow = (size_t)rowmap(lr, kb);
        size_t base = grow * S + 128 * q;
        #pragma unroll
        for (int w = 0; w < 4; ++w) {
            int j0 = 2 * txx + 32 * w;
            double2 v;
            if (own_piv && ((w >> 1) == (po >> 6))) {
                v = double2{-acc[h][w].x, -acc[h][w].y};
            } else {
                double2 old = *(const double2*)&M[base + j0];
                v = double2{old.x - acc[h][w].x, old.y - acc[h][w].y};
            }
            *(double2*)&M[base + j0] = v;
            if (own_next && ((w >> 1) == (pon >> 6)))
                *(double2*)&FN[grow * 64 + (j0 - pon)] = v;
        }
    }
}

// ---------------- kernel 4a: transpose X -> d_out (f32) at shifted positions + diag ---------
__global__ __launch_bounds__(256) void k_xt(const double* __restrict__ Mg,
                                            float* __restrict__ outF,
                                            double* __restrict__ Dg) {
    int b = blockIdx.y, t = blockIdx.x;
    int r = t & 3, c = t >> 2;
    const double* M = Mg + (size_t)b * S * S;
    __shared__ float L[64][65];
    int tid = threadIdx.x;
    int cc = tid & 63;
    #pragma unroll
    for (int rep = 0; rep < 16; ++rep) {
        int rr = rep * 4 + (tid >> 6);
        L[rr][cc] = (float)M[(size_t)(64 * r + rr) * S + 64 * c + cc];
    }
    if (r == c && tid < 64)
        Dg[(size_t)b * S + 64 * r + tid] = M[(size_t)(64 * r + tid) * S + 64 * r + tid];
    __syncthreads();
    int pp = tid & 63;
    #pragma unroll
    for (int rep = 0; rep < 16; ++rep) {
        int qq = rep * 4 + (tid >> 6);
        int orow = 64 * c + qq + 1, ocol = 64 * r + pp + 1;
        if (orow < 256 && ocol < 256)
            outF[((size_t)b * S + orow) * S + ocol] = L[pp][qq];   // = X[64r+pp][64c+qq]
    }
}

// ---------------- kernel 4b: elementwise in-place epilogue (float4) -------------------------
__global__ __launch_bounds__(256) void k_epi2(const float* __restrict__ sc,
                                              const double* __restrict__ Dg,
                                              const double* __restrict__ mb,
                                              const int* __restrict__ nb,
                                              float* __restrict__ out) {
    int b = blockIdx.y;
    int idx4 = blockIdx.x * 256 + threadIdx.x;    // 0..16383
    int i = idx4 >> 6;                            // row (wave-uniform)
    int jq = idx4 & 63;
    int n = nb[b];
    float m = (float)mb[b];
    size_t base = ((size_t)b * S + i) * S + 4 * jq;
    float4 xf = *(const float4*)(out + base);     // XFs[i][4jq..] = X[j-1][i-1]
    float4 s4 = *(const float4*)(sc + base);
    double dg = (i >= 1) ? Dg[(size_t)b * S + i - 1] : 0.0;
    float xfa[4] = {xf.x, xf.y, xf.z, xf.w};
    float sa[4]  = {s4.x, s4.y, s4.z, s4.w};
    float ra[4];
    #pragma unroll
    for (int comp = 0; comp < 4; ++comp) {
        int j = 4 * jq + comp;
        float v = 0.0f;
        if (i >= 1 && i <= n && j <= n) {
            double A = (double)expf(sa[comp] - m);
            double sub = (j >= 1) ? (double)xfa[comp] : 0.0;
            v = (float)(A * (dg - sub));
        }
        ra[comp] = v;
    }
    *(float4*)(out + base) = float4{ra[0], ra[1], ra[2], ra[3]};
}

// ---------------- launcher ----------------
extern "C" void kernel_launch(void* const* d_in, const int* in_sizes, int n_in,
                              void* d_out, int out_size, void* d_ws, size_t ws_size,
                              hipStream_t stream) {
    (void)in_sizes; (void)n_in; (void)out_size; (void)ws_size;
    const float* sc = (const float*)d_in[0];
    const unsigned char* mk = (const unsigned char*)d_in[1];
    double* ws = (double*)d_ws;

    double* M  = ws;                                 // B*256*256
    double* mb = M + (size_t)BB * S * S;             // B doubles
    int*    nb = (int*)(mb + BB);                    // B ints
    double* Dg = mb + 2 * BB;                        // B*256 doubles
    float*  partial = (float*)Dg;                    // aliases Dg (consumed before Dg written)
    float*  out = (float*)d_out;
    double* Fb0 = (double*)d_out;                    // ping-pong F panels inside d_out
    double* Fb1 = Fb0 + (size_t)BB * S * 64;         // 2 x 33.55MB = 67.1MB = |d_out| exactly

    k_max<<<dim3(8, BB), 256, 0, stream>>>(sc, partial);
    k_n<<<BB, 256, 0, stream>>>(mk, partial, mb, nb);
    k_build<<<dim3(64, BB), 256, 0, stream>>>(sc, mb, nb, M, Fb0);
    for (int kb = 0; kb < 4; ++kb) {
        const double* Fc = (kb & 1) ? Fb1 : Fb0;
        double*       Fn = (kb & 1) ? Fb0 : Fb1;
        k_step2<<<2 * BB, 512, 0, stream>>>(M, Fc, Fn, kb);
    }
    k_xt<<<dim3(16, BB), 256, 0, stream>>>(M, out, Dg);
    k_epi2<<<dim3(64, BB), 256, 0, stream>>>(sc, Dg, mb, nb, out);
}